// Round 16
// baseline (243.226 us; speedup 1.0000x reference)
//
#include <hip/hip_runtime.h>

#define BATCH 2
#define SEQ   2048
#define CH    1280
#define NH    20
#define HD    64
#define BS    (BATCH*SEQ)
#define RK    4

typedef __attribute__((ext_vector_type(2)))  float floatx2;
typedef __attribute__((ext_vector_type(4)))  short bf16x4;
typedef __attribute__((ext_vector_type(8)))  short bf16x8;
typedef __attribute__((ext_vector_type(16))) float floatx16;

__device__ __forceinline__ floatx16 mfma32(bf16x8 a, bf16x8 b, floatx16 c) {
    return __builtin_amdgcn_mfma_f32_32x32x16_bf16(a, b, c, 0, 0, 0);
}

// round-to-nearest-even f32 -> bf16
__device__ __forceinline__ unsigned short f2bf(float f) {
    unsigned int u = __float_as_uint(f);
    u += 0x7fffu + ((u >> 16) & 1u);
    return (unsigned short)(u >> 16);
}
// pack two f32 -> bf16x2 in one VGPR (round-half-up): 2 add + 1 perm
__device__ __forceinline__ unsigned int packbf(float hi, float lo) {
    unsigned int a = __float_as_uint(hi) + 0x8000u;
    unsigned int b = __float_as_uint(lo) + 0x8000u;
    return __builtin_amdgcn_perm(a, b, 0x07060302u);  // [a.hi16 : b.hi16]
}
// pack two f32 -> bf16x2 in ONE VALU op (RNE): D.lo = cvt(s0), D.hi = cvt(s1)
__device__ __forceinline__ unsigned int cvtpk(float lo, float hi) {
    unsigned int r;
    asm("v_cvt_pk_bf16_f32 %0, %1, %2" : "=v"(r) : "v"(lo), "v"(hi));
    return r;
}
__device__ __forceinline__ float fexp2(float x) {
#if __has_builtin(__builtin_amdgcn_exp2f)
    return __builtin_amdgcn_exp2f(x);
#else
    return exp2f(x);
#endif
}

// async 16B global -> LDS (DMA). LDS dest = wave-uniform base + lane*16.
__device__ __forceinline__ void cp16(const unsigned short* g, unsigned short* l) {
    __builtin_amdgcn_global_load_lds(
        (const __attribute__((address_space(1))) unsigned int*)g,
        (__attribute__((address_space(3))) unsigned int*)l, 16, 0, 0);
}

// ---------------------------------------------------------------------------
// Merged prep, float4-vectorized:
//   blocks [0, 4*F4) fold LoRA into weights -> bf16 (4 elems/thread);
//   blocks beyond cast x -> bf16 (4 elems/thread).
// ---------------------------------------------------------------------------
#define F4_BLOCKS   (CH * CH / 1024)       // 1600 per weight
#define CAST_BLOCKS (BS * CH / 1024)       // 5120

__global__ __launch_bounds__(256) void prep(
    const float* __restrict__ x,
    const float* __restrict__ Wq, const float* __restrict__ Wk,
    const float* __restrict__ Wv, const float* __restrict__ Wo,
    const float* __restrict__ Aq, const float* __restrict__ Bq,
    const float* __restrict__ Ak, const float* __restrict__ Bk,
    const float* __restrict__ Av, const float* __restrict__ Bv,
    const float* __restrict__ Ao, const float* __restrict__ Bo,
    unsigned short* __restrict__ wq_bf, unsigned short* __restrict__ wk_bf,
    unsigned short* __restrict__ wv_bf, unsigned short* __restrict__ wo_bf,
    unsigned short* __restrict__ xb)
{
    const int bx = blockIdx.x;
    if (bx < 4 * F4_BLOCKS) {
        int which = bx / F4_BLOCKS;
        int e = ((bx % F4_BLOCKS) * 256 + threadIdx.x) * 4;
        int i = e / CH, j = e % CH;
        const float *W, *A, *Bm;
        unsigned short* o;
        if (which == 0)      { W = Wq; A = Aq; Bm = Bq; o = wq_bf; }
        else if (which == 1) { W = Wk; A = Ak; Bm = Bk; o = wk_bf; }
        else if (which == 2) { W = Wv; A = Av; Bm = Bv; o = wv_bf; }
        else                 { W = Wo; A = Ao; Bm = Bo; o = wo_bf; }
        float4 acc = *(const float4*)(W + e);
#pragma unroll
        for (int r = 0; r < RK; r++) {
            float bm = Bm[i * RK + r];
            float4 a4 = *(const float4*)(A + r * CH + j);
            acc.x += bm * a4.x; acc.y += bm * a4.y;
            acc.z += bm * a4.z; acc.w += bm * a4.w;
        }
        ushort4 ov;
        ov.x = f2bf(acc.x); ov.y = f2bf(acc.y);
        ov.z = f2bf(acc.z); ov.w = f2bf(acc.w);
        *(ushort4*)(o + e) = ov;
    } else {
        int idx = ((bx - 4 * F4_BLOCKS) * 256 + threadIdx.x) * 4;
        float4 v = *(const float4*)(x + idx);
        ushort4 o;
        o.x = f2bf(v.x); o.y = f2bf(v.y); o.z = f2bf(v.z); o.w = f2bf(v.w);
        *(ushort4*)(xb + idx) = o;
    }
}

// ---------------------------------------------------------------------------
// GEMM: out[m][n] = sum_k A[m][k]*B[n][k]. 128x128 tile, BK=64, 32x32x16
// MFMA, 4 waves (wave = 64x64 via 2x2 tiles). Counted-vmcnt double-buffered
// K-loop (R15): issue K-step t+1's 8 cp16 before computing step t, then
// s_waitcnt vmcnt(8) + raw s_barrier (8 loads stay in flight). LDS 64KB.
// Staging: base + compile-time offsets (32 rows/group == 0 mod 8 -> XOR
// chunk cc g-invariant). XCD-aware bijective block swizzle (T1).
// mode 0: bf16 out (scaled). mode 2: fused V transpose -> vt via LDS
// re-transpose after the K-loop (buf0 region; final compute reads buf1).
// Interleave (K=16 PV layout): 16B chunk c of a d-row holds keys
// 16*(c>>2) + 8*(c&1) + {0..7}.
// ---------------------------------------------------------------------------
__device__ __forceinline__ void gemm128(
    const unsigned short* __restrict__ A, const unsigned short* __restrict__ B,
    unsigned short* __restrict__ obf, float oscale, int mode,
    unsigned short* __restrict__ vt)
{
    // buffer b at smem + b*16384 shorts: sa @ +0 (8192), sb @ +8192 (8192)
    __shared__ __align__(16) unsigned short smem[2 * 16384];
    const int tid = threadIdx.x;
    const int wav = tid >> 6, lane = tid & 63;
    const int n32 = lane & 31, half = lane >> 5;
    const int wr = wav >> 1, wc = wav & 1;

    // T1 XCD swizzle: nwg = 10*32 = 320 (divisible by 8), chunk = 40.
    const int wg  = blockIdx.x + gridDim.x * blockIdx.y;
    const int swz = (wg & 7) * 40 + (wg >> 3);
    const int M0 = (swz / 10) * 128, N0 = (swz % 10) * 128;

    // staging: 1024 16B-chunks per tile, 256 threads -> 4 slots each.
    // slot s = g*256+tid -> row = g*32 + (tid>>3), phys chunk tid&7,
    // logical chunk cc = (tid&7) ^ (row&7)  (g-invariant: 32 == 0 mod 8).
    const int rowt = tid >> 3, cct = (tid & 7) ^ (rowt & 7);
    const unsigned short* gA = A + (size_t)(M0 + rowt) * CH + cct * 8;
    const unsigned short* gB = B + (size_t)(N0 + rowt) * CH + cct * 8;

    auto STAGE = [&](int t, int bufb) {
        const unsigned short* gAt = gA + (size_t)t * 64;
        const unsigned short* gBt = gB + (size_t)t * 64;
        unsigned short* sa_b = smem + bufb * 16384;
        unsigned short* sb_b = sa_b + 8192;
#pragma unroll
        for (int g = 0; g < 4; g++) {
            cp16(gAt + (size_t)g * 32 * CH, sa_b + g * 2048 + wav * 512);
            cp16(gBt + (size_t)g * 32 * CH, sb_b + g * 2048 + wav * 512);
        }
    };

    const int arow0 = wr * 64 + n32, brow0 = wc * 64 + n32;

    floatx16 acc[2][2];
#pragma unroll
    for (int mt = 0; mt < 2; mt++)
#pragma unroll
        for (int nt = 0; nt < 2; nt++)
#pragma unroll
            for (int r = 0; r < 16; r++) acc[mt][nt][r] = 0.f;

    auto COMPUTE = [&](int bufb) {
        const unsigned short* sa = smem + bufb * 16384;
        const unsigned short* sb = sa + 8192;
        bf16x8 av[2][4], bv[2][4];
#pragma unroll
        for (int mt = 0; mt < 2; mt++) {
            const int ar = arow0 + mt * 32, br = brow0 + mt * 32;
#pragma unroll
            for (int ks = 0; ks < 4; ks++) {
                const int cc = ks * 2 + half;
                av[mt][ks] = *(const bf16x8*)(sa + ar * 64 + ((cc ^ (ar & 7)) << 3));
                bv[mt][ks] = *(const bf16x8*)(sb + br * 64 + ((cc ^ (br & 7)) << 3));
            }
        }
#pragma unroll
        for (int ks = 0; ks < 4; ks++)
#pragma unroll
            for (int mt = 0; mt < 2; mt++)
#pragma unroll
                for (int nt = 0; nt < 2; nt++)
                    acc[mt][nt] = mfma32(av[mt][ks], bv[nt][ks], acc[mt][nt]);
    };

    // ---- pipelined K-loop: 20 steps (CH/64), double-buffered ----
    STAGE(0, 0);
    for (int t = 0; t < 19; t++) {
        STAGE(t + 1, (t + 1) & 1);
        asm volatile("s_waitcnt vmcnt(8)" ::: "memory");
        __builtin_amdgcn_s_barrier();
        __builtin_amdgcn_sched_barrier(0);
        COMPUTE(t & 1);
        __builtin_amdgcn_s_barrier();
    }
    asm volatile("s_waitcnt vmcnt(0)" ::: "memory");
    __builtin_amdgcn_s_barrier();
    __builtin_amdgcn_sched_barrier(0);
    COMPUTE(1);   // t = 19 -> buf1

    if (mode == 2) {
        // ---- fused V transpose: regs -> LDS [ch_local][s swizzled] ----
        // (uses buf0 region; final compute read buf1 -> no collision)
        // b64 unit u = s_local/4 stored at phys unit u ^ (d_local&31).
#pragma unroll
        for (int mt = 0; mt < 2; mt++) {
#pragma unroll
            for (int nt = 0; nt < 2; nt++) {
                const int dl = wc * 64 + nt * 32 + n32;
#pragma unroll
                for (int j = 0; j < 4; j++) {
                    const int u = wr * 16 + mt * 8 + 2 * j + half;
                    uint2 w;
                    w.x = packbf(acc[mt][nt][4 * j + 1], acc[mt][nt][4 * j + 0]);
                    w.y = packbf(acc[mt][nt][4 * j + 3], acc[mt][nt][4 * j + 2]);
                    *(uint2*)(smem + dl * 128 + ((u ^ n32) << 2)) = w;
                }
            }
        }
        __syncthreads();
        // ---- LDS -> vt, coalesced uint4, interleaved-key chunk assembly ----
        // K=16 PV layout: chunk pc holds keys 32*g32 + 16*p + 8*hb + {0..7}
        const int b = M0 >> 11;                       // batch of this M-tile
        const int s_in = M0 & (SEQ - 1);
#pragma unroll
        for (int g = 0; g < 8; g++) {
            int cid = g * 256 + tid;
            int dl = cid >> 4, pc = cid & 15;
            int g32 = pc >> 2, p = (pc & 3) >> 1, hb = pc & 1;
            int u1 = 8 * g32 + 4 * p + 2 * hb;        // keys 32g32+16p+8hb..+3
            int sw = dl & 31;
            uint2 r1 = *(const uint2*)(smem + dl * 128 + ((u1 ^ sw) << 2));
            uint2 r2 = *(const uint2*)(smem + dl * 128 + (((u1 + 1) ^ sw) << 2));
            int ch = N0 + dl, h = ch >> 6, d = ch & 63;
            uint4 val; val.x = r1.x; val.y = r1.y; val.z = r2.x; val.w = r2.y;
            *(uint4*)(vt + (size_t)((b * NH + h) * HD + d) * SEQ + s_in + pc * 8) = val;
        }
        return;
    }

    // epilogue: C/D layout col = lane&31, row = (r&3) + 8*(r>>2) + 4*half
#pragma unroll
    for (int mt = 0; mt < 2; mt++) {
#pragma unroll
        for (int nt = 0; nt < 2; nt++) {
            const int col = N0 + wc * 64 + nt * 32 + n32;
#pragma unroll
            for (int r = 0; r < 16; r++) {
                size_t row = (size_t)(M0 + wr * 64 + mt * 32 +
                                      (r & 3) + 8 * (r >> 2) + 4 * half);
                obf[row * CH + col] = f2bf(acc[mt][nt][r] * oscale);
            }
        }
    }
}

__global__ __launch_bounds__(256) void gemm_qkv(
    const unsigned short* __restrict__ xb,
    const unsigned short* __restrict__ wq, const unsigned short* __restrict__ wk,
    const unsigned short* __restrict__ wv,
    unsigned short* __restrict__ q, unsigned short* __restrict__ k,
    unsigned short* __restrict__ vt)
{
    const unsigned short* w = blockIdx.z == 0 ? wq : blockIdx.z == 1 ? wk : wv;
    unsigned short* o = blockIdx.z == 0 ? q : k;
    // q pre-scaled by 1/sqrt(64) * log2(e): softmax becomes a bare exp2
    float scale = blockIdx.z == 0 ? 0.18033688011112042f : 1.0f;
    int mode = blockIdx.z == 2 ? 2 : 0;
    gemm128(xb, w, o, scale, mode, vt);
}

// ---------------------------------------------------------------------------
// Output-projection GEMM (R14-verified): 64x128 tiles, 4 waves (256 thr).
// 640 blocks = 2.5/CU, XCD-chunked (640 = 8x80). Wave w owns N-quarter w
// (32 cols), 2 M-subtiles. LDS 24KB. f32 out + bias. UNCHANGED.
// ---------------------------------------------------------------------------
__global__ __launch_bounds__(256) void gemm_o64(
    const unsigned short* __restrict__ A, const unsigned short* __restrict__ B,
    const float* __restrict__ bias, float* __restrict__ out)
{
    __shared__ __align__(16) unsigned short smem[64 * 64 + 128 * 64];
    unsigned short* sa = smem;
    unsigned short* sb = smem + 64 * 64;
    const int tid = threadIdx.x;
    const int wav = tid >> 6, lane = tid & 63;
    const int n32 = lane & 31, half = lane >> 5;

    // T1 XCD swizzle: nwg = 64*10 = 640 = 8*80, chunked bijective remap.
    const int wg  = blockIdx.x;
    const int swz = (wg & 7) * 80 + (wg >> 3);
    const int M0 = (swz / 10) * 64, N0 = (swz % 10) * 128;

    // staging: A 512 chunks -> 2 slots/thread; B 1024 chunks -> 4 slots.
    // base + const offsets (32 rows/group == 0 mod 8 -> cc g-invariant).
    const int rowt = tid >> 3, cct = (tid & 7) ^ (rowt & 7);
    const unsigned short* gA = A + (size_t)(M0 + rowt) * CH + cct * 8;
    const unsigned short* gB = B + (size_t)(N0 + rowt) * CH + cct * 8;

    const int brow = wav * 32 + n32;

    floatx16 acc[2];
#pragma unroll
    for (int mt = 0; mt < 2; mt++)
#pragma unroll
        for (int r = 0; r < 16; r++) acc[mt][r] = 0.f;

    for (int k0 = 0; k0 < CH; k0 += 64) {
#pragma unroll
        for (int g = 0; g < 2; g++)
            cp16(gA + (size_t)g * 32 * CH, sa + g * 2048 + wav * 512);
#pragma unroll
        for (int g = 0; g < 4; g++)
            cp16(gB + (size_t)g * 32 * CH, sb + g * 2048 + wav * 512);
        gA += 64; gB += 64;
        __syncthreads();

        bf16x8 av[2][4], bv[4];
#pragma unroll
        for (int ks = 0; ks < 4; ks++) {
            const int cc = ks * 2 + half;
#pragma unroll
            for (int mt = 0; mt < 2; mt++) {
                const int ar = mt * 32 + n32;
                av[mt][ks] = *(const bf16x8*)(sa + ar * 64 + ((cc ^ (ar & 7)) << 3));
            }
            bv[ks] = *(const bf16x8*)(sb + brow * 64 + ((cc ^ (brow & 7)) << 3));
        }
#pragma unroll
        for (int ks = 0; ks < 4; ks++)
#pragma unroll
            for (int mt = 0; mt < 2; mt++)
                acc[mt] = mfma32(av[mt][ks], bv[ks], acc[mt]);
        __syncthreads();
    }

    // epilogue: col = lane-mapped (B side), row = reg-mapped (A side)
    const int col = N0 + wav * 32 + n32;
    const float bv2 = bias[col];
#pragma unroll
    for (int mt = 0; mt < 2; mt++) {
#pragma unroll
        for (int r = 0; r < 16; r++) {
            size_t row = (size_t)(M0 + mt * 32 + (r & 3) + 8 * (r >> 2) + 4 * half);
            out[row * CH + col] = acc[mt][r] + bv2;
        }
    }
}

// ---------------------------------------------------------------------------
// Transposed flash attention (R10 structure: XCD swizzle + cvt_pk; verified
// 61.0-62.5us, FETCH 15.4MB = K/V L2-resident). R16: s_setprio(1) wraps the
// pure-MFMA clusters (T5 — never isolated on this schedule; dbuf creates
// {staging vs MFMA} wave role diversity = the m191-positive regime).
// Double-buffered K/V, counted vmcnt(4), raw barriers, K=16 PV via
// v_permlane32_swap_b32, wave role (qg, kh), key-half combine at epilogue.
// ---------------------------------------------------------------------------
__global__ __launch_bounds__(512, 4) void attention(
    const unsigned short* __restrict__ q, const unsigned short* __restrict__ k,
    const unsigned short* __restrict__ vt, unsigned short* __restrict__ c_bf)
{
    // two 32KB buffers: buf b at smem + b*16384 shorts
    //   k_lds [128 keys][64 d] swz at +0, v_lds [64 d][128 key-il] at +8192
    // epilogue reuses buf0 as the f32 combine buffer (two phases).
    __shared__ __align__(16) unsigned short smem[2 * (128 * 64 + 64 * 128)];

    const int tid = threadIdx.x, wav = tid >> 6, lane = tid & 63;
    const int n32 = lane & 31, half = lane >> 5;
    const int qg = wav >> 1, kh = wav & 1;

    // T1 XCD swizzle: nwg = 16*40 = 640 = 8*80 -> bijective chunked remap.
    // chunk of 80 consecutive swz = 5 whole (b,h) heads per XCD.
    const int wg  = blockIdx.x + gridDim.x * blockIdx.y;
    const int swz = (wg & 7) * 80 + (wg >> 3);
    const int q0 = (swz & 15) * 128;
    const int bh = swz >> 4, b = bh / NH, h = bh % NH;

    // Q as B-operand (held all kernel): frag f -> d = 16f + 8*half + j
    const size_t qrow = (size_t)(b * SEQ + q0 + qg * 32 + n32);
    bf16x8 qf[4];
#pragma unroll
    for (int f = 0; f < 4; f++)
        qf[f] = *(const bf16x8*)(q + qrow * CH + h * HD + f * 16 + half * 8);

    // staging bases. K tile: 1024 chunks, 512 thr -> 2 cp16 (rows tid>>3, +64)
    // V tile: 2 cp16 (d rows tid>>4, +32)
    const int rowk = tid >> 3, cck = (tid & 7) ^ (rowk & 7);
    const int rowv = tid >> 4, ccv = (tid & 15) ^ (rowv & 15);
    const unsigned short* gk0 = k + (size_t)(b * SEQ + rowk) * CH + h * HD + cck * 8;
    const unsigned short* gv0 = vt + (size_t)(bh * HD + rowv) * SEQ + ccv * 8;

    auto STAGE = [&](int t, int bufb) {
        const unsigned short* gk = gk0 + (size_t)t * 128 * CH;
        const unsigned short* gv = gv0 + t * 128;
        unsigned short* lk = smem + bufb * 16384 + wav * 512;
        unsigned short* lv = smem + bufb * 16384 + 8192 + wav * 512;
#pragma unroll
        for (int g = 0; g < 2; g++) {
            cp16(gk + (size_t)g * 64 * CH, lk + g * 4096);
            cp16(gv + (size_t)g * 32 * SEQ, lv + g * 4096);
        }
    };

    floatx2 ps = {0.f, 0.f};
    floatx16 acc[2];
#pragma unroll
    for (int dt = 0; dt < 2; dt++)
#pragma unroll
        for (int r = 0; r < 16; r++) acc[dt][r] = 0.f;

    auto COMPUTE = [&](int bufb) {
        const unsigned short* k_lds = smem + bufb * 16384;
        const unsigned short* v_lds = k_lds + 8192;
#pragma unroll
        for (int ktl = 0; ktl < 2; ktl++) {
            const int kt = kh * 2 + ktl;   // this wave's key subtiles
            // ---- S^T tile (32 keys x 32 q): A = K rows, B = Q row ----
            const int keyrow = kt * 32 + n32;
            const unsigned short* kr = k_lds + keyrow * 64;
            floatx16 st;
#pragma unroll
            for (int r = 0; r < 16; r++) st[r] = 0.f;
            __builtin_amdgcn_s_setprio(1);
#pragma unroll
            for (int f = 0; f < 4; f++) {
                int phys = (2 * f + half) ^ (keyrow & 7);
                bf16x8 kf = *(const bf16x8*)(kr + phys * 8);
                st = mfma32(kf, qf[f], st);
            }
            __builtin_amdgcn_s_setprio(0);

            // ---- per 16-key group: exp2 + psum + cvt_pk + half-swap + PV ----
#pragma unroll
            for (int pp = 0; pp < 2; pp++) {
                float p[8];
#pragma unroll
                for (int r = 0; r < 8; r++) p[r] = fexp2(st[8 * pp + r]);
#pragma unroll
                for (int j = 0; j < 4; j++)
                    ps += (floatx2){p[2 * j], p[2 * j + 1]};
                // own quads: lo = keys 4h+{0..3}, hi = keys 4h+8+{0..3}
                unsigned int lo0 = cvtpk(p[0], p[1]);
                unsigned int lo1 = cvtpk(p[2], p[3]);
                unsigned int hi0 = cvtpk(p[4], p[5]);
                unsigned int hi1 = cvtpk(p[6], p[7]);
                // swap hi-lanes(lo) <-> lo-lanes(hi): after this
                //   frag = [lo0,lo1,hi0,hi1] = keys 8*half + {0..7}  (both halves)
                asm volatile("v_permlane32_swap_b32 %0, %1"
                             : "+v"(lo0), "+v"(hi0));
                asm volatile("v_permlane32_swap_b32 %0, %1"
                             : "+v"(lo1), "+v"(hi1));
                union { unsigned int u[4]; bf16x8 v; } pb;
                pb.u[0] = lo0; pb.u[1] = lo1; pb.u[2] = hi0; pb.u[3] = hi1;
                const int ct = kt * 4 + pp * 2 + half;
                __builtin_amdgcn_s_setprio(1);
#pragma unroll
                for (int dt = 0; dt < 2; dt++) {
                    const int drow = dt * 32 + n32;
                    int phys = ct ^ (drow & 15);
                    bf16x8 vv = *(const bf16x8*)(v_lds + drow * 128 + phys * 8);
                    acc[dt] = mfma32(vv, pb.v, acc[dt]);
                }
                __builtin_amdgcn_s_setprio(0);
            }
        }
    };

    // ---- pipelined main loop: 16 tiles, double-buffered ----
    STAGE(0, 0);
    for (int it = 0; it < 15; it++) {
        STAGE(it + 1, (it + 1) & 1);
        asm volatile("s_waitcnt vmcnt(4)" ::: "memory");
        __builtin_amdgcn_s_barrier();
        __builtin_amdgcn_sched_barrier(0);
        COMPUTE(it & 1);
        __builtin_amdgcn_s_barrier();
    }
    asm volatile("s_waitcnt vmcnt(0)" ::: "memory");
    __builtin_amdgcn_s_barrier();
    __builtin_amdgcn_sched_barrier(0);
    COMPUTE(1);

    // ---- combine key-halves across wave pairs via LDS (two phases), write O
    // exchange layout: [qg&1][lane] stride 33 f32 (32 acc + 1 psum) = 16.9KB
    float psum = ps.x + ps.y;
    float* ex = (float*)smem;
#pragma unroll
    for (int p2 = 0; p2 < 2; p2++) {
        __syncthreads();
        if (kh == 1 && (qg >> 1) == p2) {
            float* dst = ex + (size_t)((qg & 1) * 64 + lane) * 33;
#pragma unroll
            for (int dt = 0; dt < 2; dt++)
#pragma unroll
                for (int r = 0; r < 16; r++) dst[dt * 16 + r] = acc[dt][r];
            dst[32] = psum;
        }
        __syncthreads();
        if (kh == 0 && (qg >> 1) == p2) {
            const float* src = ex + (size_t)((qg & 1) * 64 + lane) * 33;
#pragma unroll
            for (int dt = 0; dt < 2; dt++)
#pragma unroll
                for (int r = 0; r < 16; r++) acc[dt][r] += src[dt * 16 + r];
            psum += src[32];
        }
    }
    if (kh) return;

    // denom = own half-lane partial + partner half-lane partial
    float tot = psum + __shfl_xor(psum, 32, 64);
    float rinv = __frcp_rn(tot);
    const size_t obase = qrow * CH + h * HD;
#pragma unroll
    for (int dt = 0; dt < 2; dt++) {
#pragma unroll
        for (int jj = 0; jj < 4; jj++) {
            int d = dt * 32 + 8 * jj + 4 * half;
            uint2 o2;
            o2.x = packbf(acc[dt][4 * jj + 1] * rinv, acc[dt][4 * jj + 0] * rinv);
            o2.y = packbf(acc[dt][4 * jj + 3] * rinv, acc[dt][4 * jj + 2] * rinv);
            *(uint2*)(c_bf + obase + d) = o2;
        }
    }
}

// ---------------------------------------------------------------------------
extern "C" void kernel_launch(void* const* d_in, const int* in_sizes, int n_in,
                              void* d_out, int out_size, void* d_ws, size_t ws_size,
                              hipStream_t stream)
{
    const float* x  = (const float*)d_in[0];
    const float* Wq = (const float*)d_in[1];
    const float* Wk = (const float*)d_in[2];
    const float* Wv = (const float*)d_in[3];
    const float* Wo = (const float*)d_in[4];
    const float* bo = (const float*)d_in[5];
    const float* Aq = (const float*)d_in[6];
    const float* Bq = (const float*)d_in[7];
    const float* Ak = (const float*)d_in[8];
    const float* Bk = (const float*)d_in[9];
    const float* Av = (const float*)d_in[10];
    const float* Bv = (const float*)d_in[11];
    const float* Ao = (const float*)d_in[12];
    const float* Bo = (const float*)d_in[13];
    float* out = (float*)d_out;

    char* ws = (char*)d_ws;
    size_t off = 0;
    auto alloc = [&](size_t bytes) -> void* {
        void* p = ws + off; off += (bytes + 255) & ~(size_t)255; return p;
    };
    const size_t WB = (size_t)CH * CH, XB = (size_t)BS * CH;
    unsigned short* wq_bf = (unsigned short*)alloc(WB * 2);
    unsigned short* wk_bf = (unsigned short*)alloc(WB * 2);
    unsigned short* wv_bf = (unsigned short*)alloc(WB * 2);
    unsigned short* wo_bf = (unsigned short*)alloc(WB * 2);
    unsigned short* x_bf  = (unsigned short*)alloc(XB * 2);
    unsigned short* q_bf  = (unsigned short*)alloc(XB * 2);
    unsigned short* k_bf  = (unsigned short*)alloc(XB * 2);
    unsigned short* vt_bf = (unsigned short*)alloc(XB * 2);
    unsigned short* c_bf  = (unsigned short*)alloc(XB * 2);
    (void)ws_size; (void)n_in; (void)in_sizes; (void)out_size;

    prep<<<dim3(4 * F4_BLOCKS + CAST_BLOCKS), 256, 0, stream>>>(
        x, Wq, Wk, Wv, Wo, Aq, Bq, Ak, Bk, Av, Bv, Ao, Bo,
        wq_bf, wk_bf, wv_bf, wo_bf, x_bf);

    // q,k projections + V fused-transpose into vt
    gemm_qkv<<<dim3(CH / 128, BS / 128, 3), 256, 0, stream>>>(
        x_bf, wq_bf, wk_bf, wv_bf, q_bf, k_bf, vt_bf);

    attention<<<dim3(SEQ / 128, BATCH * NH), 512, 0, stream>>>(
        q_bf, k_bf, vt_bf, c_bf);

    gemm_o64<<<dim3((BS / 64) * (CH / 128)), 256, 0, stream>>>(
        c_bf, wo_bf, bo, out);
}

// Round 17
// 238.051 us; speedup vs baseline: 1.0217x; 1.0217x over previous
//
#include <hip/hip_runtime.h>

#define BATCH 2
#define SEQ   2048
#define CH    1280
#define NH    20
#define HD    64
#define BS    (BATCH*SEQ)
#define RK    4

typedef __attribute__((ext_vector_type(2)))  float floatx2;
typedef __attribute__((ext_vector_type(4)))  short bf16x4;
typedef __attribute__((ext_vector_type(8)))  short bf16x8;
typedef __attribute__((ext_vector_type(16))) float floatx16;

__device__ __forceinline__ floatx16 mfma32(bf16x8 a, bf16x8 b, floatx16 c) {
    return __builtin_amdgcn_mfma_f32_32x32x16_bf16(a, b, c, 0, 0, 0);
}

// round-to-nearest-even f32 -> bf16
__device__ __forceinline__ unsigned short f2bf(float f) {
    unsigned int u = __float_as_uint(f);
    u += 0x7fffu + ((u >> 16) & 1u);
    return (unsigned short)(u >> 16);
}
// pack two f32 -> bf16x2 in one VGPR (round-half-up): 2 add + 1 perm
__device__ __forceinline__ unsigned int packbf(float hi, float lo) {
    unsigned int a = __float_as_uint(hi) + 0x8000u;
    unsigned int b = __float_as_uint(lo) + 0x8000u;
    return __builtin_amdgcn_perm(a, b, 0x07060302u);  // [a.hi16 : b.hi16]
}
// pack two f32 -> bf16x2 in ONE VALU op (RNE): D.lo = cvt(s0), D.hi = cvt(s1)
__device__ __forceinline__ unsigned int cvtpk(float lo, float hi) {
    unsigned int r;
    asm("v_cvt_pk_bf16_f32 %0, %1, %2" : "=v"(r) : "v"(lo), "v"(hi));
    return r;
}
__device__ __forceinline__ float fexp2(float x) {
#if __has_builtin(__builtin_amdgcn_exp2f)
    return __builtin_amdgcn_exp2f(x);
#else
    return exp2f(x);
#endif
}

// async 16B global -> LDS (DMA). LDS dest = wave-uniform base + lane*16.
__device__ __forceinline__ void cp16(const unsigned short* g, unsigned short* l) {
    __builtin_amdgcn_global_load_lds(
        (const __attribute__((address_space(1))) unsigned int*)g,
        (__attribute__((address_space(3))) unsigned int*)l, 16, 0, 0);
}

// ---------------------------------------------------------------------------
// Merged prep, float4-vectorized:
//   blocks [0, 4*F4) fold LoRA into weights -> bf16 (4 elems/thread);
//   blocks beyond cast x -> bf16 (4 elems/thread).
// ---------------------------------------------------------------------------
#define F4_BLOCKS   (CH * CH / 1024)       // 1600 per weight
#define CAST_BLOCKS (BS * CH / 1024)       // 5120

__global__ __launch_bounds__(256) void prep(
    const float* __restrict__ x,
    const float* __restrict__ Wq, const float* __restrict__ Wk,
    const float* __restrict__ Wv, const float* __restrict__ Wo,
    const float* __restrict__ Aq, const float* __restrict__ Bq,
    const float* __restrict__ Ak, const float* __restrict__ Bk,
    const float* __restrict__ Av, const float* __restrict__ Bv,
    const float* __restrict__ Ao, const float* __restrict__ Bo,
    unsigned short* __restrict__ wq_bf, unsigned short* __restrict__ wk_bf,
    unsigned short* __restrict__ wv_bf, unsigned short* __restrict__ wo_bf,
    unsigned short* __restrict__ xb)
{
    const int bx = blockIdx.x;
    if (bx < 4 * F4_BLOCKS) {
        int which = bx / F4_BLOCKS;
        int e = ((bx % F4_BLOCKS) * 256 + threadIdx.x) * 4;
        int i = e / CH, j = e % CH;
        const float *W, *A, *Bm;
        unsigned short* o;
        if (which == 0)      { W = Wq; A = Aq; Bm = Bq; o = wq_bf; }
        else if (which == 1) { W = Wk; A = Ak; Bm = Bk; o = wk_bf; }
        else if (which == 2) { W = Wv; A = Av; Bm = Bv; o = wv_bf; }
        else                 { W = Wo; A = Ao; Bm = Bo; o = wo_bf; }
        float4 acc = *(const float4*)(W + e);
#pragma unroll
        for (int r = 0; r < RK; r++) {
            float bm = Bm[i * RK + r];
            float4 a4 = *(const float4*)(A + r * CH + j);
            acc.x += bm * a4.x; acc.y += bm * a4.y;
            acc.z += bm * a4.z; acc.w += bm * a4.w;
        }
        ushort4 ov;
        ov.x = f2bf(acc.x); ov.y = f2bf(acc.y);
        ov.z = f2bf(acc.z); ov.w = f2bf(acc.w);
        *(ushort4*)(o + e) = ov;
    } else {
        int idx = ((bx - 4 * F4_BLOCKS) * 256 + threadIdx.x) * 4;
        float4 v = *(const float4*)(x + idx);
        ushort4 o;
        o.x = f2bf(v.x); o.y = f2bf(v.y); o.z = f2bf(v.z); o.w = f2bf(v.w);
        *(ushort4*)(xb + idx) = o;
    }
}

// ---------------------------------------------------------------------------
// GEMM: out[m][n] = sum_k A[m][k]*B[n][k]. 128x128 tile, BK=64, 32x32x16
// MFMA, 4 waves (wave = 64x64 via 2x2 tiles). Counted-vmcnt double-buffered
// K-loop (R15-verified): issue K-step t+1's 8 cp16 before computing step t,
// then s_waitcnt vmcnt(8) + raw s_barrier (8 loads stay in flight). LDS 64KB.
// Staging: base + compile-time offsets (32 rows/group == 0 mod 8 -> XOR
// chunk cc g-invariant). XCD-aware bijective block swizzle (T1).
// mode 0: bf16 out (scaled). mode 2: fused V transpose -> vt via LDS
// re-transpose after the K-loop (buf0 region; final compute reads buf1).
// Interleave (K=16 PV layout): 16B chunk c of a d-row holds keys
// 16*(c>>2) + 8*(c&1) + {0..7}.
// ---------------------------------------------------------------------------
__device__ __forceinline__ void gemm128(
    const unsigned short* __restrict__ A, const unsigned short* __restrict__ B,
    unsigned short* __restrict__ obf, float oscale, int mode,
    unsigned short* __restrict__ vt)
{
    // buffer b at smem + b*16384 shorts: sa @ +0 (8192), sb @ +8192 (8192)
    __shared__ __align__(16) unsigned short smem[2 * 16384];
    const int tid = threadIdx.x;
    const int wav = tid >> 6, lane = tid & 63;
    const int n32 = lane & 31, half = lane >> 5;
    const int wr = wav >> 1, wc = wav & 1;

    // T1 XCD swizzle: nwg = 10*32 = 320 (divisible by 8), chunk = 40.
    const int wg  = blockIdx.x + gridDim.x * blockIdx.y;
    const int swz = (wg & 7) * 40 + (wg >> 3);
    const int M0 = (swz / 10) * 128, N0 = (swz % 10) * 128;

    // staging: 1024 16B-chunks per tile, 256 threads -> 4 slots each.
    // slot s = g*256+tid -> row = g*32 + (tid>>3), phys chunk tid&7,
    // logical chunk cc = (tid&7) ^ (row&7)  (g-invariant: 32 == 0 mod 8).
    const int rowt = tid >> 3, cct = (tid & 7) ^ (rowt & 7);
    const unsigned short* gA = A + (size_t)(M0 + rowt) * CH + cct * 8;
    const unsigned short* gB = B + (size_t)(N0 + rowt) * CH + cct * 8;

    auto STAGE = [&](int t, int bufb) {
        const unsigned short* gAt = gA + (size_t)t * 64;
        const unsigned short* gBt = gB + (size_t)t * 64;
        unsigned short* sa_b = smem + bufb * 16384;
        unsigned short* sb_b = sa_b + 8192;
#pragma unroll
        for (int g = 0; g < 4; g++) {
            cp16(gAt + (size_t)g * 32 * CH, sa_b + g * 2048 + wav * 512);
            cp16(gBt + (size_t)g * 32 * CH, sb_b + g * 2048 + wav * 512);
        }
    };

    const int arow0 = wr * 64 + n32, brow0 = wc * 64 + n32;

    floatx16 acc[2][2];
#pragma unroll
    for (int mt = 0; mt < 2; mt++)
#pragma unroll
        for (int nt = 0; nt < 2; nt++)
#pragma unroll
            for (int r = 0; r < 16; r++) acc[mt][nt][r] = 0.f;

    auto COMPUTE = [&](int bufb) {
        const unsigned short* sa = smem + bufb * 16384;
        const unsigned short* sb = sa + 8192;
        bf16x8 av[2][4], bv[2][4];
#pragma unroll
        for (int mt = 0; mt < 2; mt++) {
            const int ar = arow0 + mt * 32, br = brow0 + mt * 32;
#pragma unroll
            for (int ks = 0; ks < 4; ks++) {
                const int cc = ks * 2 + half;
                av[mt][ks] = *(const bf16x8*)(sa + ar * 64 + ((cc ^ (ar & 7)) << 3));
                bv[mt][ks] = *(const bf16x8*)(sb + br * 64 + ((cc ^ (br & 7)) << 3));
            }
        }
#pragma unroll
        for (int ks = 0; ks < 4; ks++)
#pragma unroll
            for (int mt = 0; mt < 2; mt++)
#pragma unroll
                for (int nt = 0; nt < 2; nt++)
                    acc[mt][nt] = mfma32(av[mt][ks], bv[mt == 0 ? nt : nt][ks], acc[mt][nt]);
    };

    // ---- pipelined K-loop: 20 steps (CH/64), double-buffered ----
    STAGE(0, 0);
    for (int t = 0; t < 19; t++) {
        STAGE(t + 1, (t + 1) & 1);
        asm volatile("s_waitcnt vmcnt(8)" ::: "memory");
        __builtin_amdgcn_s_barrier();
        __builtin_amdgcn_sched_barrier(0);
        COMPUTE(t & 1);
        __builtin_amdgcn_s_barrier();
    }
    asm volatile("s_waitcnt vmcnt(0)" ::: "memory");
    __builtin_amdgcn_s_barrier();
    __builtin_amdgcn_sched_barrier(0);
    COMPUTE(1);   // t = 19 -> buf1

    if (mode == 2) {
        // ---- fused V transpose: regs -> LDS [ch_local][s swizzled] ----
        // (uses buf0 region; final compute read buf1 -> no collision)
        // b64 unit u = s_local/4 stored at phys unit u ^ (d_local&31).
#pragma unroll
        for (int mt = 0; mt < 2; mt++) {
#pragma unroll
            for (int nt = 0; nt < 2; nt++) {
                const int dl = wc * 64 + nt * 32 + n32;
#pragma unroll
                for (int j = 0; j < 4; j++) {
                    const int u = wr * 16 + mt * 8 + 2 * j + half;
                    uint2 w;
                    w.x = packbf(acc[mt][nt][4 * j + 1], acc[mt][nt][4 * j + 0]);
                    w.y = packbf(acc[mt][nt][4 * j + 3], acc[mt][nt][4 * j + 2]);
                    *(uint2*)(smem + dl * 128 + ((u ^ n32) << 2)) = w;
                }
            }
        }
        __syncthreads();
        // ---- LDS -> vt, coalesced uint4, interleaved-key chunk assembly ----
        // K=16 PV layout: chunk pc holds keys 32*g32 + 16*p + 8*hb + {0..7}
        const int b = M0 >> 11;                       // batch of this M-tile
        const int s_in = M0 & (SEQ - 1);
#pragma unroll
        for (int g = 0; g < 8; g++) {
            int cid = g * 256 + tid;
            int dl = cid >> 4, pc = cid & 15;
            int g32 = pc >> 2, p = (pc & 3) >> 1, hb = pc & 1;
            int u1 = 8 * g32 + 4 * p + 2 * hb;        // keys 32g32+16p+8hb..+3
            int sw = dl & 31;
            uint2 r1 = *(const uint2*)(smem + dl * 128 + ((u1 ^ sw) << 2));
            uint2 r2 = *(const uint2*)(smem + dl * 128 + (((u1 + 1) ^ sw) << 2));
            int ch = N0 + dl, h = ch >> 6, d = ch & 63;
            uint4 val; val.x = r1.x; val.y = r1.y; val.z = r2.x; val.w = r2.y;
            *(uint4*)(vt + (size_t)((b * NH + h) * HD + d) * SEQ + s_in + pc * 8) = val;
        }
        return;
    }

    // epilogue: C/D layout col = lane&31, row = (r&3) + 8*(r>>2) + 4*half
#pragma unroll
    for (int mt = 0; mt < 2; mt++) {
#pragma unroll
        for (int nt = 0; nt < 2; nt++) {
            const int col = N0 + wc * 64 + nt * 32 + n32;
#pragma unroll
            for (int r = 0; r < 16; r++) {
                size_t row = (size_t)(M0 + wr * 64 + mt * 32 +
                                      (r & 3) + 8 * (r >> 2) + 4 * half);
                obf[row * CH + col] = f2bf(acc[mt][nt][r] * oscale);
            }
        }
    }
}

__global__ __launch_bounds__(256) void gemm_qkv(
    const unsigned short* __restrict__ xb,
    const unsigned short* __restrict__ wq, const unsigned short* __restrict__ wk,
    const unsigned short* __restrict__ wv,
    unsigned short* __restrict__ q, unsigned short* __restrict__ k,
    unsigned short* __restrict__ vt)
{
    const unsigned short* w = blockIdx.z == 0 ? wq : blockIdx.z == 1 ? wk : wv;
    unsigned short* o = blockIdx.z == 0 ? q : k;
    // q pre-scaled by 1/sqrt(64) * log2(e): softmax becomes a bare exp2
    float scale = blockIdx.z == 0 ? 0.18033688011112042f : 1.0f;
    int mode = blockIdx.z == 2 ? 2 : 0;
    gemm128(xb, w, o, scale, mode, vt);
}

// ---------------------------------------------------------------------------
// Output-projection GEMM (R14-verified): 64x128 tiles, 4 waves (256 thr).
// 640 blocks = 2.5/CU, XCD-chunked (640 = 8x80). Wave w owns N-quarter w
// (32 cols), 2 M-subtiles. LDS 24KB. f32 out + bias.
// ---------------------------------------------------------------------------
__global__ __launch_bounds__(256) void gemm_o64(
    const unsigned short* __restrict__ A, const unsigned short* __restrict__ B,
    const float* __restrict__ bias, float* __restrict__ out)
{
    __shared__ __align__(16) unsigned short smem[64 * 64 + 128 * 64];
    unsigned short* sa = smem;
    unsigned short* sb = smem + 64 * 64;
    const int tid = threadIdx.x;
    const int wav = tid >> 6, lane = tid & 63;
    const int n32 = lane & 31, half = lane >> 5;

    // T1 XCD swizzle: nwg = 64*10 = 640 = 8*80, chunked bijective remap.
    const int wg  = blockIdx.x;
    const int swz = (wg & 7) * 80 + (wg >> 3);
    const int M0 = (swz / 10) * 64, N0 = (swz % 10) * 128;

    // staging: A 512 chunks -> 2 slots/thread; B 1024 chunks -> 4 slots.
    // base + const offsets (32 rows/group == 0 mod 8 -> cc g-invariant).
    const int rowt = tid >> 3, cct = (tid & 7) ^ (rowt & 7);
    const unsigned short* gA = A + (size_t)(M0 + rowt) * CH + cct * 8;
    const unsigned short* gB = B + (size_t)(N0 + rowt) * CH + cct * 8;

    const int brow = wav * 32 + n32;

    floatx16 acc[2];
#pragma unroll
    for (int mt = 0; mt < 2; mt++)
#pragma unroll
        for (int r = 0; r < 16; r++) acc[mt][r] = 0.f;

    for (int k0 = 0; k0 < CH; k0 += 64) {
#pragma unroll
        for (int g = 0; g < 2; g++)
            cp16(gA + (size_t)g * 32 * CH, sa + g * 2048 + wav * 512);
#pragma unroll
        for (int g = 0; g < 4; g++)
            cp16(gB + (size_t)g * 32 * CH, sb + g * 2048 + wav * 512);
        gA += 64; gB += 64;
        __syncthreads();

        bf16x8 av[2][4], bv[4];
#pragma unroll
        for (int ks = 0; ks < 4; ks++) {
            const int cc = ks * 2 + half;
#pragma unroll
            for (int mt = 0; mt < 2; mt++) {
                const int ar = mt * 32 + n32;
                av[mt][ks] = *(const bf16x8*)(sa + ar * 64 + ((cc ^ (ar & 7)) << 3));
            }
            bv[ks] = *(const bf16x8*)(sb + brow * 64 + ((cc ^ (brow & 7)) << 3));
        }
#pragma unroll
        for (int ks = 0; ks < 4; ks++)
#pragma unroll
            for (int mt = 0; mt < 2; mt++)
                acc[mt] = mfma32(av[mt][ks], bv[ks], acc[mt]);
        __syncthreads();
    }

    // epilogue: col = lane-mapped (B side), row = reg-mapped (A side)
    const int col = N0 + wav * 32 + n32;
    const float bv2 = bias[col];
#pragma unroll
    for (int mt = 0; mt < 2; mt++) {
#pragma unroll
        for (int r = 0; r < 16; r++) {
            size_t row = (size_t)(M0 + mt * 32 + (r & 3) + 8 * (r >> 2) + 4 * half);
            out[row * CH + col] = acc[mt][r] + bv2;
        }
    }
}

// ---------------------------------------------------------------------------
// Transposed flash attention (R10 structure, R15-verified 61.0-62.5us,
// FETCH 15.4MB = K/V L2-resident; setprio removed — R16 showed -4.3us).
// Double-buffered K/V, counted vmcnt(4), raw barriers, K=16 PV via
// v_permlane32_swap_b32, wave role (qg, kh), key-half combine at epilogue.
// ---------------------------------------------------------------------------
__global__ __launch_bounds__(512, 4) void attention(
    const unsigned short* __restrict__ q, const unsigned short* __restrict__ k,
    const unsigned short* __restrict__ vt, unsigned short* __restrict__ c_bf)
{
    // two 32KB buffers: buf b at smem + b*16384 shorts
    //   k_lds [128 keys][64 d] swz at +0, v_lds [64 d][128 key-il] at +8192
    // epilogue reuses buf0 as the f32 combine buffer (two phases).
    __shared__ __align__(16) unsigned short smem[2 * (128 * 64 + 64 * 128)];

    const int tid = threadIdx.x, wav = tid >> 6, lane = tid & 63;
    const int n32 = lane & 31, half = lane >> 5;
    const int qg = wav >> 1, kh = wav & 1;

    // T1 XCD swizzle: nwg = 16*40 = 640 = 8*80 -> bijective chunked remap.
    // chunk of 80 consecutive swz = 5 whole (b,h) heads per XCD.
    const int wg  = blockIdx.x + gridDim.x * blockIdx.y;
    const int swz = (wg & 7) * 80 + (wg >> 3);
    const int q0 = (swz & 15) * 128;
    const int bh = swz >> 4, b = bh / NH, h = bh % NH;

    // Q as B-operand (held all kernel): frag f -> d = 16f + 8*half + j
    const size_t qrow = (size_t)(b * SEQ + q0 + qg * 32 + n32);
    bf16x8 qf[4];
#pragma unroll
    for (int f = 0; f < 4; f++)
        qf[f] = *(const bf16x8*)(q + qrow * CH + h * HD + f * 16 + half * 8);

    // staging bases. K tile: 1024 chunks, 512 thr -> 2 cp16 (rows tid>>3, +64)
    // V tile: 2 cp16 (d rows tid>>4, +32)
    const int rowk = tid >> 3, cck = (tid & 7) ^ (rowk & 7);
    const int rowv = tid >> 4, ccv = (tid & 15) ^ (rowv & 15);
    const unsigned short* gk0 = k + (size_t)(b * SEQ + rowk) * CH + h * HD + cck * 8;
    const unsigned short* gv0 = vt + (size_t)(bh * HD + rowv) * SEQ + ccv * 8;

    auto STAGE = [&](int t, int bufb) {
        const unsigned short* gk = gk0 + (size_t)t * 128 * CH;
        const unsigned short* gv = gv0 + t * 128;
        unsigned short* lk = smem + bufb * 16384 + wav * 512;
        unsigned short* lv = smem + bufb * 16384 + 8192 + wav * 512;
#pragma unroll
        for (int g = 0; g < 2; g++) {
            cp16(gk + (size_t)g * 64 * CH, lk + g * 4096);
            cp16(gv + (size_t)g * 32 * SEQ, lv + g * 4096);
        }
    };

    floatx2 ps = {0.f, 0.f};
    floatx16 acc[2];
#pragma unroll
    for (int dt = 0; dt < 2; dt++)
#pragma unroll
        for (int r = 0; r < 16; r++) acc[dt][r] = 0.f;

    auto COMPUTE = [&](int bufb) {
        const unsigned short* k_lds = smem + bufb * 16384;
        const unsigned short* v_lds = k_lds + 8192;
#pragma unroll
        for (int ktl = 0; ktl < 2; ktl++) {
            const int kt = kh * 2 + ktl;   // this wave's key subtiles
            // ---- S^T tile (32 keys x 32 q): A = K rows, B = Q row ----
            const int keyrow = kt * 32 + n32;
            const unsigned short* kr = k_lds + keyrow * 64;
            floatx16 st;
#pragma unroll
            for (int r = 0; r < 16; r++) st[r] = 0.f;
#pragma unroll
            for (int f = 0; f < 4; f++) {
                int phys = (2 * f + half) ^ (keyrow & 7);
                bf16x8 kf = *(const bf16x8*)(kr + phys * 8);
                st = mfma32(kf, qf[f], st);
            }

            // ---- per 16-key group: exp2 + psum + cvt_pk + half-swap + PV ----
#pragma unroll
            for (int pp = 0; pp < 2; pp++) {
                float p[8];
#pragma unroll
                for (int r = 0; r < 8; r++) p[r] = fexp2(st[8 * pp + r]);
#pragma unroll
                for (int j = 0; j < 4; j++)
                    ps += (floatx2){p[2 * j], p[2 * j + 1]};
                // own quads: lo = keys 4h+{0..3}, hi = keys 4h+8+{0..3}
                unsigned int lo0 = cvtpk(p[0], p[1]);
                unsigned int lo1 = cvtpk(p[2], p[3]);
                unsigned int hi0 = cvtpk(p[4], p[5]);
                unsigned int hi1 = cvtpk(p[6], p[7]);
                // swap hi-lanes(lo) <-> lo-lanes(hi): after this
                //   frag = [lo0,lo1,hi0,hi1] = keys 8*half + {0..7}  (both halves)
                asm volatile("v_permlane32_swap_b32 %0, %1"
                             : "+v"(lo0), "+v"(hi0));
                asm volatile("v_permlane32_swap_b32 %0, %1"
                             : "+v"(lo1), "+v"(hi1));
                union { unsigned int u[4]; bf16x8 v; } pb;
                pb.u[0] = lo0; pb.u[1] = lo1; pb.u[2] = hi0; pb.u[3] = hi1;
                const int ct = kt * 4 + pp * 2 + half;
#pragma unroll
                for (int dt = 0; dt < 2; dt++) {
                    const int drow = dt * 32 + n32;
                    int phys = ct ^ (drow & 15);
                    bf16x8 vv = *(const bf16x8*)(v_lds + drow * 128 + phys * 8);
                    acc[dt] = mfma32(vv, pb.v, acc[dt]);
                }
            }
        }
    };

    // ---- pipelined main loop: 16 tiles, double-buffered ----
    STAGE(0, 0);
    for (int it = 0; it < 15; it++) {
        STAGE(it + 1, (it + 1) & 1);
        asm volatile("s_waitcnt vmcnt(4)" ::: "memory");
        __builtin_amdgcn_s_barrier();
        __builtin_amdgcn_sched_barrier(0);
        COMPUTE(it & 1);
        __builtin_amdgcn_s_barrier();
    }
    asm volatile("s_waitcnt vmcnt(0)" ::: "memory");
    __builtin_amdgcn_s_barrier();
    __builtin_amdgcn_sched_barrier(0);
    COMPUTE(1);

    // ---- combine key-halves across wave pairs via LDS (two phases), write O
    // exchange layout: [qg&1][lane] stride 33 f32 (32 acc + 1 psum) = 16.9KB
    float psum = ps.x + ps.y;
    float* ex = (float*)smem;
#pragma unroll
    for (int p2 = 0; p2 < 2; p2++) {
        __syncthreads();
        if (kh == 1 && (qg >> 1) == p2) {
            float* dst = ex + (size_t)((qg & 1) * 64 + lane) * 33;
#pragma unroll
            for (int dt = 0; dt < 2; dt++)
#pragma unroll
                for (int r = 0; r < 16; r++) dst[dt * 16 + r] = acc[dt][r];
            dst[32] = psum;
        }
        __syncthreads();
        if (kh == 0 && (qg >> 1) == p2) {
            const float* src = ex + (size_t)((qg & 1) * 64 + lane) * 33;
#pragma unroll
            for (int dt = 0; dt < 2; dt++)
#pragma unroll
                for (int r = 0; r < 16; r++) acc[dt][r] += src[dt * 16 + r];
            psum += src[32];
        }
    }
    if (kh) return;

    // denom = own half-lane partial + partner half-lane partial
    float tot = psum + __shfl_xor(psum, 32, 64);
    float rinv = __frcp_rn(tot);
    const size_t obase = qrow * CH + h * HD;
#pragma unroll
    for (int dt = 0; dt < 2; dt++) {
#pragma unroll
        for (int jj = 0; jj < 4; jj++) {
            int d = dt * 32 + 8 * jj + 4 * half;
            uint2 o2;
            o2.x = packbf(acc[dt][4 * jj + 1] * rinv, acc[dt][4 * jj + 0] * rinv);
            o2.y = packbf(acc[dt][4 * jj + 3] * rinv, acc[dt][4 * jj + 2] * rinv);
            *(uint2*)(c_bf + obase + d) = o2;
        }
    }
}

// ---------------------------------------------------------------------------
extern "C" void kernel_launch(void* const* d_in, const int* in_sizes, int n_in,
                              void* d_out, int out_size, void* d_ws, size_t ws_size,
                              hipStream_t stream)
{
    const float* x  = (const float*)d_in[0];
    const float* Wq = (const float*)d_in[1];
    const float* Wk = (const float*)d_in[2];
    const float* Wv = (const float*)d_in[3];
    const float* Wo = (const float*)d_in[4];
    const float* bo = (const float*)d_in[5];
    const float* Aq = (const float*)d_in[6];
    const float* Bq = (const float*)d_in[7];
    const float* Ak = (const float*)d_in[8];
    const float* Bk = (const float*)d_in[9];
    const float* Av = (const float*)d_in[10];
    const float* Bv = (const float*)d_in[11];
    const float* Ao = (const float*)d_in[12];
    const float* Bo = (const float*)d_in[13];
    float* out = (float*)d_out;

    char* ws = (char*)d_ws;
    size_t off = 0;
    auto alloc = [&](size_t bytes) -> void* {
        void* p = ws + off; off += (bytes + 255) & ~(size_t)255; return p;
    };
    const size_t WB = (size_t)CH * CH, XB = (size_t)BS * CH;
    unsigned short* wq_bf = (unsigned short*)alloc(WB * 2);
    unsigned short* wk_bf = (unsigned short*)alloc(WB * 2);
    unsigned short* wv_bf = (unsigned short*)alloc(WB * 2);
    unsigned short* wo_bf = (unsigned short*)alloc(WB * 2);
    unsigned short* x_bf  = (unsigned short*)alloc(XB * 2);
    unsigned short* q_bf  = (unsigned short*)alloc(XB * 2);
    unsigned short* k_bf  = (unsigned short*)alloc(XB * 2);
    unsigned short* vt_bf = (unsigned short*)alloc(XB * 2);
    unsigned short* c_bf  = (unsigned short*)alloc(XB * 2);
    (void)ws_size; (void)n_in; (void)in_sizes; (void)out_size;

    prep<<<dim3(4 * F4_BLOCKS + CAST_BLOCKS), 256, 0, stream>>>(
        x, Wq, Wk, Wv, Wo, Aq, Bq, Ak, Bk, Av, Bv, Ao, Bo,
        wq_bf, wk_bf, wv_bf, wo_bf, x_bf);

    // q,k projections + V fused-transpose into vt
    gemm_qkv<<<dim3(CH / 128, BS / 128, 3), 256, 0, stream>>>(
        x_bf, wq_bf, wk_bf, wv_bf, q_bf, k_bf, vt_bf);

    attention<<<dim3(SEQ / 128, BATCH * NH), 512, 0, stream>>>(
        q_bf, k_bf, vt_bf, c_bf);

    gemm_o64<<<dim3((BS / 64) * (CH / 128)), 256, 0, stream>>>(
        c_bf, wo_bf, bo, out);
}